// Round 27
// baseline (135.375 us; speedup 1.0000x reference)
//
#include <hip/hip_runtime.h>
#include <hip/hip_bf16.h>

#define HH 128
#define WW 128
#define HWSZ (HH * WW)   // 16384
#define CC 64
#define BB 2
#define KK 7
#define K2 49
#define ROWE 280         // bf16 elems/padded row: [Eph0 70][Eph1 70][Oph0 70][Oph1 70]

typedef unsigned int u32;

__device__ __forceinline__ int clampi(int v, int lo, int hi) {
    return v < lo ? lo : (v > hi ? hi : v);
}

__device__ __forceinline__ uint4 ld16(const __hip_bfloat16* src) {
    uint4 d; __builtin_memcpy(&d, src, 16); return d;   // 4B-aligned dwordx4
}

// 8 packed bf16 (4 dwords) -> 8 fp32. elem 2k = lo half of dword k.
__device__ __forceinline__ void unpack8(uint4 d, float* f) {
    f[0] = __uint_as_float(d.x << 16); f[1] = __uint_as_float(d.x & 0xffff0000u);
    f[2] = __uint_as_float(d.y << 16); f[3] = __uint_as_float(d.y & 0xffff0000u);
    f[4] = __uint_as_float(d.z << 16); f[5] = __uint_as_float(d.z & 0xffff0000u);
    f[6] = __uint_as_float(d.w << 16); f[7] = __uint_as_float(d.w & 0xffff0000u);
}

__device__ __forceinline__ unsigned short f2bf(float v) {
    __hip_bfloat16 b = __float2bfloat16(v);
    return *reinterpret_cast<unsigned short*>(&b);
}

// per-lane window offset: 7-neighbor window = first 7 elems of one aligned 16B load
__device__ __forceinline__ int lane_off(int w) {
    const int parity = w & 1, t = w >> 1, phase = t & 1;
    return parity * 140 + phase * 70 + (t - phase);
}

// ---------------------------------------------------------------------------
// K1: K/Q/V = relu(W @ x) as a register-blocked GEMM (r20 structure,
// measured ~17.5 us). Grid 768 = xcd(8) x [pbl16 x slice6].
// ---------------------------------------------------------------------------
__global__ __launch_bounds__(256) void kqv_kernel(
    const float* __restrict__ x,  const float* __restrict__ Wk,
    const float* __restrict__ Wq, const float* __restrict__ Wv,
    __hip_bfloat16* __restrict__ Kp, __hip_bfloat16* __restrict__ Qt,
    __hip_bfloat16* __restrict__ Vp)
{
    __shared__ __align__(16) float Wl[64][32];            // 8 KB [c][och_local]
    __shared__ __hip_bfloat16 T[32][2][128];              // 16 KB [ol][row][w]

    const int xcd   = blockIdx.x & 7;
    const int t     = blockIdx.x >> 3;        // 0..95
    const int pbl   = t & 15;
    const int slice = t >> 4;                 // 0..5
    const int pb    = xcd * 16 + pbl;         // 0..127
    const int a     = slice >> 1;             // 0:K 1:Q 2:V
    const int ohb   = (slice & 1) * 32;       // och base within array
    const int b0    = pb >> 6;
    const int h0    = 2 * (pb & 63);
    const int hw0   = (pb & 63) * 256;

    const float* Wsel = (a == 0) ? Wk : (a == 1) ? Wq : Wv;

    for (int idx = threadIdx.x; idx < 2048; idx += 256) {
        const int c  = idx >> 5;
        const int ol = idx & 31;
        Wl[c][ol] = Wsel[(ohb + ol) * CC + c];
    }
    __syncthreads();

    const int quad = threadIdx.x & 63;        // 4 consecutive px
    const int oct  = threadIdx.x >> 6;        // 8 consecutive och

    const float* xbase = x + (size_t)b0 * CC * HWSZ + hw0 + quad * 4;

    float acc[8][4];
#pragma unroll
    for (int i = 0; i < 8; ++i)
#pragma unroll
        for (int j = 0; j < 4; ++j) acc[i][j] = 0.f;

#pragma unroll 4
    for (int c = 0; c < CC; ++c) {
        const float4 x4 = *(const float4*)(xbase + (size_t)c * HWSZ);
        const float xj[4] = {x4.x, x4.y, x4.z, x4.w};
        float w8[8];
        *(float4*)(w8)     = *(const float4*)&Wl[c][oct * 8];
        *(float4*)(w8 + 4) = *(const float4*)&Wl[c][oct * 8 + 4];
#pragma unroll
        for (int i = 0; i < 8; ++i)
#pragma unroll
            for (int j = 0; j < 4; ++j)
                acc[i][j] = fmaf(w8[i], xj[j], acc[i][j]);
    }

#pragma unroll
    for (int i = 0; i < 8; ++i) {
        const int ol = oct * 8 + i;
#pragma unroll
        for (int j = 0; j < 4; ++j) {
            const int px = quad * 4 + j;
            T[ol][px >> 7][px & 127] = __float2bfloat16(fmaxf(acc[i][j], 0.f));
        }
    }
    __syncthreads();

    if (a == 1) {
        for (int idx = threadIdx.x; idx < 1024; idx += 256) {
            const int px = idx >> 2;
            const int ck = idx & 3;
            unsigned short e[8];
#pragma unroll
            for (int u = 0; u < 8; ++u) {
                __hip_bfloat16 bv = T[ck * 8 + u][px >> 7][px & 127];
                e[u] = *reinterpret_cast<unsigned short*>(&bv);
            }
            __hip_bfloat16* dst = Qt +
                (size_t)(b0 * HWSZ + hw0 + px) * CC + ohb + ck * 8;
            __builtin_memcpy(dst, e, 16);
        }
    } else {
        __hip_bfloat16* arrp = (a == 0) ? Kp : Vp;
        for (int idx = threadIdx.x; idx < 2240; idx += 256) {
            const int row_id = idx / 35;           // 0..63
            const int cki    = idx - row_id * 35;  // 0..34
            const int ol     = row_id >> 1;
            const int rr     = row_id & 1;
            unsigned short e[8];
#pragma unroll
            for (int u = 0; u < 8; ++u) {
                const int q      = cki * 8 + u;           // 0..279
                const int parity = q >= 140 ? 1 : 0;
                const int sslot  = q - parity * 140;
                const int phase  = sslot >= 70 ? 1 : 0;
                const int local  = sslot - phase * 70;
                const int pix    = clampi(2 * (local - (phase ? 2 : 3)) + parity,
                                          0, 127);
                __hip_bfloat16 bv = T[ol][rr][pix];
                e[u] = *reinterpret_cast<unsigned short*>(&bv);
            }
            __hip_bfloat16* dst = arrp +
                ((size_t)(b0 * CC + ohb + ol) * HH + (h0 + rr)) * ROWE + cki * 8;
            __builtin_memcpy(dst, e, 16);
        }
    }
}

// ---------------------------------------------------------------------------
// K2: FULLY FUSED attention + Wt conv + residual.
// __launch_bounds__(256, 4): grid caps this kernel at 4 waves/SIMD anyway,
// so the allocator's default 64-VGPR (8-wave) target buys nothing -- cap at
// 128 instead and let the 2-channel-pair unroll keep 14 window loads in
// flight during each channel's unpack+FMA burst (intra-wave pipelining).
// Compute order per sc[k] unchanged (ci then ci+1) -> bit-identical output.
// ---------------------------------------------------------------------------
__global__ __launch_bounds__(256, 4) void attn_kernel(
    const __hip_bfloat16* __restrict__ Kp, const __hip_bfloat16* __restrict__ Qt,
    const __hip_bfloat16* __restrict__ Vp, const float* __restrict__ Wt,
    const float* __restrict__ x, float* __restrict__ out)
{
    __shared__ float part[2][K2][33];
    __shared__ __align__(16) float Wt_l[64][65];           // padded: no 4-way
    __shared__ __align__(16) __hip_bfloat16 O_l[32][72];   // padded

    const int xcd  = blockIdx.x & 7;
    const int s    = blockIdx.x >> 3;       // 0..127
    const int bh   = xcd * 32 + (s >> 2);   // 0..255
    const int wseg = s & 3;
    const int b    = bh >> 7;
    const int h    = bh & 127;

    const int tid = threadIdx.x;
    const int px  = (tid & 15) | ((tid >> 7) << 4);   // 0..31
    const int cq  = (tid >> 4) & 7;                   // 0..7
    const int w   = wseg * 32 + px;                   // 0..127
    const int p   = b * HWSZ + h * WW + w;
    const int c0  = cq * 8;

    // stage Wt (overlaps phase A; covered by the post-phase-A barrier)
    for (int idx = tid; idx < 4096; idx += 256)
        Wt_l[idx >> 6][idx & 63] = Wt[idx];

    int hn[KK];
#pragma unroll
    for (int i = 0; i < KK; ++i) hn[i] = clampi(h + 2 * i - 6, 0, HH - 1);

    const int loff = lane_off(w);
    const size_t cstride = (size_t)HH * ROWE;
    const __hip_bfloat16* Kc = Kp + (size_t)(b * CC + c0) * cstride + loff;
    const __hip_bfloat16* Vc = Vp + (size_t)(b * CC + c0) * cstride + loff;

    float qf[8];
    unpack8(ld16(Qt + (size_t)p * CC + c0), qf);

    // ---- Phase A: partial scores, 2-channel-pair pipelined ----
    float sc[K2];
#pragma unroll
    for (int k = 0; k < K2; ++k) sc[k] = 0.f;

#pragma unroll
    for (int cp = 0; cp < 4; ++cp) {
        const __hip_bfloat16* baseA = Kc + (size_t)(2 * cp) * cstride;
        const __hip_bfloat16* baseB = Kc + (size_t)(2 * cp + 1) * cstride;
        uint4 kdA[KK], kdB[KK];
#pragma unroll
        for (int i = 0; i < KK; ++i) kdA[i] = ld16(baseA + (size_t)hn[i] * ROWE);
#pragma unroll
        for (int i = 0; i < KK; ++i) kdB[i] = ld16(baseB + (size_t)hn[i] * ROWE);
        const float qA = qf[2 * cp], qB = qf[2 * cp + 1];
#pragma unroll
        for (int i = 0; i < KK; ++i) {
            float kf[8];
            unpack8(kdA[i], kf);
#pragma unroll
            for (int j = 0; j < KK; ++j)
                sc[i * KK + j] = fmaf(kf[j], qA, sc[i * KK + j]);
        }
#pragma unroll
        for (int i = 0; i < KK; ++i) {
            float kf[8];
            unpack8(kdB[i], kf);
#pragma unroll
            for (int j = 0; j < KK; ++j)
                sc[i * KK + j] = fmaf(kf[j], qB, sc[i * KK + j]);
        }
    }

    // ---- cq-reduction: 4 cqs per wave via shfl, then 2 slices via LDS ----
#pragma unroll
    for (int k = 0; k < K2; ++k) sc[k] += __shfl_xor(sc[k], 16, 64);
#pragma unroll
    for (int k = 0; k < K2; ++k) sc[k] += __shfl_xor(sc[k], 32, 64);

    const int sl = (tid >> 6) & 1;
    if (((tid >> 4) & 3) == 0) {
#pragma unroll
        for (int k = 0; k < K2; ++k) part[sl][k][px] = sc[k];
    }
    __syncthreads();

    // ---- softmax (per thread, redundant x8, deterministic) ----
#pragma unroll
    for (int k = 0; k < K2; ++k) sc[k] = part[0][k][px] + part[1][k][px];
    float m = sc[0];
#pragma unroll
    for (int k = 1; k < K2; ++k) m = fmaxf(m, sc[k]);
    float sum = 0.f;
#pragma unroll
    for (int k = 0; k < K2; ++k) { sc[k] = __expf(sc[k] - m); sum += sc[k]; }
    const float inv = 1.f / sum;
#pragma unroll
    for (int k = 0; k < K2; ++k) sc[k] *= inv;

    // residual loads early (independent of phase B; hides under PV compute)
    const int hw = h * WW + w;
    float fin[8];
#pragma unroll
    for (int i = 0; i < 8; ++i)
        fin[i] = x[((size_t)(b * CC) + c0 + i) * HWSZ + hw];

    // ---- Phase B: V-aggregate, 2-channel-pair pipelined ----
    unsigned short ob[8];
#pragma unroll
    for (int cp = 0; cp < 4; ++cp) {
        const __hip_bfloat16* baseA = Vc + (size_t)(2 * cp) * cstride;
        const __hip_bfloat16* baseB = Vc + (size_t)(2 * cp + 1) * cstride;
        uint4 vdA[KK], vdB[KK];
#pragma unroll
        for (int i = 0; i < KK; ++i) vdA[i] = ld16(baseA + (size_t)hn[i] * ROWE);
#pragma unroll
        for (int i = 0; i < KK; ++i) vdB[i] = ld16(baseB + (size_t)hn[i] * ROWE);
        float accA = 0.f, accB = 0.f;
#pragma unroll
        for (int i = 0; i < KK; ++i) {
            float vf[8];
            unpack8(vdA[i], vf);
#pragma unroll
            for (int j = 0; j < KK; ++j)
                accA = fmaf(vf[j], sc[i * KK + j], accA);
        }
#pragma unroll
        for (int i = 0; i < KK; ++i) {
            float vf[8];
            unpack8(vdB[i], vf);
#pragma unroll
            for (int j = 0; j < KK; ++j)
                accB = fmaf(vf[j], sc[i * KK + j], accB);
        }
        ob[2 * cp]     = f2bf(accA);
        ob[2 * cp + 1] = f2bf(accB);
    }

    u32 od[4];
#pragma unroll
    for (int i = 0; i < 4; ++i)
        od[i] = (u32)ob[2 * i] | ((u32)ob[2 * i + 1] << 16);
    __builtin_memcpy(&O_l[px][c0], od, 16);
    __syncthreads();

    // ---- fused Wt conv + residual ----
#pragma unroll
    for (int c8 = 0; c8 < 8; ++c8) {
        uint4 d = *(const uint4*)&O_l[px][c8 * 8];
        float oc[8];
        unpack8(d, oc);
#pragma unroll
        for (int cc = 0; cc < 8; ++cc) {
            const int c = c8 * 8 + cc;
#pragma unroll
            for (int i = 0; i < 8; ++i)
                fin[i] = fmaf(Wt_l[c0 + i][c], oc[cc], fin[i]);
        }
    }

#pragma unroll
    for (int i = 0; i < 8; ++i)
        out[((size_t)(b * CC) + c0 + i) * HWSZ + hw] = fin[i];
}

// ---------------------------------------------------------------------------
extern "C" void kernel_launch(void* const* d_in, const int* in_sizes, int n_in,
                              void* d_out, int out_size, void* d_ws, size_t ws_size,
                              hipStream_t stream)
{
    const float* x  = (const float*)d_in[0];
    const float* Wk = (const float*)d_in[1];
    const float* Wq = (const float*)d_in[2];
    const float* Wv = (const float*)d_in[3];
    const float* Wt = (const float*)d_in[4];
    float* out = (float*)d_out;

    const size_t KP_ELEMS = (size_t)BB * CC * HH * ROWE;  // 4,587,520 bf16
    __hip_bfloat16* Kp = (__hip_bfloat16*)d_ws;
    __hip_bfloat16* Vp = Kp + KP_ELEMS;
    __hip_bfloat16* Qt = Vp + KP_ELEMS;                   // total ws 22.6 MB

    hipLaunchKernelGGL(kqv_kernel, dim3(768), dim3(256), 0, stream,
                       x, Wk, Wq, Wv, Kp, Qt, Vp);
    hipLaunchKernelGGL(attn_kernel, dim3(1024), dim3(256), 0, stream,
                       Kp, Qt, Vp, Wt, x, out);
}

// Round 28
// 65.572 us; speedup vs baseline: 2.0645x; 2.0645x over previous
//
#include <hip/hip_runtime.h>
#include <hip/hip_bf16.h>

#define HH 128
#define WW 128
#define HWSZ (HH * WW)   // 16384
#define CC 64
#define BB 2
#define KK 7
#define K2 49
#define ROWE 280         // bf16 elems/padded row: [Eph0 70][Eph1 70][Oph0 70][Oph1 70]

typedef unsigned int u32;

__device__ __forceinline__ int clampi(int v, int lo, int hi) {
    return v < lo ? lo : (v > hi ? hi : v);
}

__device__ __forceinline__ uint4 ld16(const __hip_bfloat16* src) {
    uint4 d; __builtin_memcpy(&d, src, 16); return d;   // 4B-aligned dwordx4
}

// 8 packed bf16 (4 dwords) -> 8 fp32. elem 2k = lo half of dword k.
__device__ __forceinline__ void unpack8(uint4 d, float* f) {
    f[0] = __uint_as_float(d.x << 16); f[1] = __uint_as_float(d.x & 0xffff0000u);
    f[2] = __uint_as_float(d.y << 16); f[3] = __uint_as_float(d.y & 0xffff0000u);
    f[4] = __uint_as_float(d.z << 16); f[5] = __uint_as_float(d.z & 0xffff0000u);
    f[6] = __uint_as_float(d.w << 16); f[7] = __uint_as_float(d.w & 0xffff0000u);
}

__device__ __forceinline__ unsigned short f2bf(float v) {
    __hip_bfloat16 b = __float2bfloat16(v);
    return *reinterpret_cast<unsigned short*>(&b);
}

// per-lane window offset: 7-neighbor window = first 7 elems of one aligned 16B load
__device__ __forceinline__ int lane_off(int w) {
    const int parity = w & 1, t = w >> 1, phase = t & 1;
    return parity * 140 + phase * 70 + (t - phase);
}

// ---------------------------------------------------------------------------
// K1: K/Q/V = relu(W @ x) as a register-blocked GEMM (r20 structure,
// measured ~17.5 us). Grid 768 = xcd(8) x [pbl16 x slice6].
// ---------------------------------------------------------------------------
__global__ __launch_bounds__(256) void kqv_kernel(
    const float* __restrict__ x,  const float* __restrict__ Wk,
    const float* __restrict__ Wq, const float* __restrict__ Wv,
    __hip_bfloat16* __restrict__ Kp, __hip_bfloat16* __restrict__ Qt,
    __hip_bfloat16* __restrict__ Vp)
{
    __shared__ __align__(16) float Wl[64][32];            // 8 KB [c][och_local]
    __shared__ __hip_bfloat16 T[32][2][128];              // 16 KB [ol][row][w]

    const int xcd   = blockIdx.x & 7;
    const int t     = blockIdx.x >> 3;        // 0..95
    const int pbl   = t & 15;
    const int slice = t >> 4;                 // 0..5
    const int pb    = xcd * 16 + pbl;         // 0..127
    const int a     = slice >> 1;             // 0:K 1:Q 2:V
    const int ohb   = (slice & 1) * 32;       // och base within array
    const int b0    = pb >> 6;
    const int h0    = 2 * (pb & 63);
    const int hw0   = (pb & 63) * 256;

    const float* Wsel = (a == 0) ? Wk : (a == 1) ? Wq : Wv;

    for (int idx = threadIdx.x; idx < 2048; idx += 256) {
        const int c  = idx >> 5;
        const int ol = idx & 31;
        Wl[c][ol] = Wsel[(ohb + ol) * CC + c];
    }
    __syncthreads();

    const int quad = threadIdx.x & 63;        // 4 consecutive px
    const int oct  = threadIdx.x >> 6;        // 8 consecutive och

    const float* xbase = x + (size_t)b0 * CC * HWSZ + hw0 + quad * 4;

    float acc[8][4];
#pragma unroll
    for (int i = 0; i < 8; ++i)
#pragma unroll
        for (int j = 0; j < 4; ++j) acc[i][j] = 0.f;

#pragma unroll 4
    for (int c = 0; c < CC; ++c) {
        const float4 x4 = *(const float4*)(xbase + (size_t)c * HWSZ);
        const float xj[4] = {x4.x, x4.y, x4.z, x4.w};
        float w8[8];
        *(float4*)(w8)     = *(const float4*)&Wl[c][oct * 8];
        *(float4*)(w8 + 4) = *(const float4*)&Wl[c][oct * 8 + 4];
#pragma unroll
        for (int i = 0; i < 8; ++i)
#pragma unroll
            for (int j = 0; j < 4; ++j)
                acc[i][j] = fmaf(w8[i], xj[j], acc[i][j]);
    }

#pragma unroll
    for (int i = 0; i < 8; ++i) {
        const int ol = oct * 8 + i;
#pragma unroll
        for (int j = 0; j < 4; ++j) {
            const int px = quad * 4 + j;
            T[ol][px >> 7][px & 127] = __float2bfloat16(fmaxf(acc[i][j], 0.f));
        }
    }
    __syncthreads();

    if (a == 1) {
        for (int idx = threadIdx.x; idx < 1024; idx += 256) {
            const int px = idx >> 2;
            const int ck = idx & 3;
            unsigned short e[8];
#pragma unroll
            for (int u = 0; u < 8; ++u) {
                __hip_bfloat16 bv = T[ck * 8 + u][px >> 7][px & 127];
                e[u] = *reinterpret_cast<unsigned short*>(&bv);
            }
            __hip_bfloat16* dst = Qt +
                (size_t)(b0 * HWSZ + hw0 + px) * CC + ohb + ck * 8;
            __builtin_memcpy(dst, e, 16);
        }
    } else {
        __hip_bfloat16* arrp = (a == 0) ? Kp : Vp;
        for (int idx = threadIdx.x; idx < 2240; idx += 256) {
            const int row_id = idx / 35;           // 0..63
            const int cki    = idx - row_id * 35;  // 0..34
            const int ol     = row_id >> 1;
            const int rr     = row_id & 1;
            unsigned short e[8];
#pragma unroll
            for (int u = 0; u < 8; ++u) {
                const int q      = cki * 8 + u;           // 0..279
                const int parity = q >= 140 ? 1 : 0;
                const int sslot  = q - parity * 140;
                const int phase  = sslot >= 70 ? 1 : 0;
                const int local  = sslot - phase * 70;
                const int pix    = clampi(2 * (local - (phase ? 2 : 3)) + parity,
                                          0, 127);
                __hip_bfloat16 bv = T[ol][rr][pix];
                e[u] = *reinterpret_cast<unsigned short*>(&bv);
            }
            __hip_bfloat16* dst = arrp +
                ((size_t)(b0 * CC + ohb + ol) * HH + (h0 + rr)) * ROWE + cki * 8;
            __builtin_memcpy(dst, e, 16);
        }
    }
}

// ---------------------------------------------------------------------------
// K2: FULLY FUSED attention + Wt conv + residual (r24/r26, 46.7 us).
// Grid 1024 = xcd(8) x [bh32 x wseg4], 256 thr:
// px = (tid&15)|((tid>>7)<<4) (0..31), cq = (tid>>4)&7 (8 channels).
// ---------------------------------------------------------------------------
__global__ __launch_bounds__(256) void attn_kernel(
    const __hip_bfloat16* __restrict__ Kp, const __hip_bfloat16* __restrict__ Qt,
    const __hip_bfloat16* __restrict__ Vp, const float* __restrict__ Wt,
    const float* __restrict__ x, float* __restrict__ out)
{
    __shared__ float part[2][K2][33];
    __shared__ __align__(16) float Wt_l[64][65];           // padded: no 4-way
    __shared__ __align__(16) __hip_bfloat16 O_l[32][72];   // padded

    const int xcd  = blockIdx.x & 7;
    const int s    = blockIdx.x >> 3;       // 0..127
    const int bh   = xcd * 32 + (s >> 2);   // 0..255
    const int wseg = s & 3;
    const int b    = bh >> 7;
    const int h    = bh & 127;

    const int tid = threadIdx.x;
    const int px  = (tid & 15) | ((tid >> 7) << 4);   // 0..31
    const int cq  = (tid >> 4) & 7;                   // 0..7
    const int w   = wseg * 32 + px;                   // 0..127
    const int p   = b * HWSZ + h * WW + w;
    const int c0  = cq * 8;

    // stage Wt (overlaps phase A; covered by the post-phase-A barrier)
    for (int idx = tid; idx < 4096; idx += 256)
        Wt_l[idx >> 6][idx & 63] = Wt[idx];

    int hn[KK];
#pragma unroll
    for (int i = 0; i < KK; ++i) hn[i] = clampi(h + 2 * i - 6, 0, HH - 1);

    const int loff = lane_off(w);
    const size_t cstride = (size_t)HH * ROWE;
    const __hip_bfloat16* Kc = Kp + (size_t)(b * CC + c0) * cstride + loff;
    const __hip_bfloat16* Vc = Vp + (size_t)(b * CC + c0) * cstride + loff;

    float qf[8];
    unpack8(ld16(Qt + (size_t)p * CC + c0), qf);

    // ---- Phase A: partial scores over 8 channels ----
    float sc[K2];
#pragma unroll
    for (int k = 0; k < K2; ++k) sc[k] = 0.f;

    for (int ci = 0; ci < 8; ++ci) {
        uint4 kd[KK];
        const __hip_bfloat16* base = Kc + (size_t)ci * cstride;
#pragma unroll
        for (int i = 0; i < KK; ++i) kd[i] = ld16(base + (size_t)hn[i] * ROWE);
        const float qv = qf[ci];
#pragma unroll
        for (int i = 0; i < KK; ++i) {
            float kf[8];
            unpack8(kd[i], kf);
#pragma unroll
            for (int j = 0; j < KK; ++j)
                sc[i * KK + j] = fmaf(kf[j], qv, sc[i * KK + j]);
        }
    }

    // ---- cq-reduction: 4 cqs per wave via shfl, then 2 slices via LDS ----
#pragma unroll
    for (int k = 0; k < K2; ++k) sc[k] += __shfl_xor(sc[k], 16, 64);
#pragma unroll
    for (int k = 0; k < K2; ++k) sc[k] += __shfl_xor(sc[k], 32, 64);

    const int sl = (tid >> 6) & 1;
    if (((tid >> 4) & 3) == 0) {
#pragma unroll
        for (int k = 0; k < K2; ++k) part[sl][k][px] = sc[k];
    }
    __syncthreads();

    // ---- softmax (per thread, redundant x8, deterministic) ----
#pragma unroll
    for (int k = 0; k < K2; ++k) sc[k] = part[0][k][px] + part[1][k][px];
    float m = sc[0];
#pragma unroll
    for (int k = 1; k < K2; ++k) m = fmaxf(m, sc[k]);
    float sum = 0.f;
#pragma unroll
    for (int k = 0; k < K2; ++k) { sc[k] = __expf(sc[k] - m); sum += sc[k]; }
    const float inv = 1.f / sum;
#pragma unroll
    for (int k = 0; k < K2; ++k) sc[k] *= inv;

    // residual loads early (independent of phase B; hides under PV compute)
    const int hw = h * WW + w;
    float fin[8];
#pragma unroll
    for (int i = 0; i < 8; ++i)
        fin[i] = x[((size_t)(b * CC) + c0 + i) * HWSZ + hw];

    // ---- Phase B: V-aggregate for this thread's 8 output channels ----
    unsigned short ob[8];
    for (int ci = 0; ci < 8; ++ci) {
        uint4 vd[KK];
        const __hip_bfloat16* base = Vc + (size_t)ci * cstride;
#pragma unroll
        for (int i = 0; i < KK; ++i) vd[i] = ld16(base + (size_t)hn[i] * ROWE);
        float acc = 0.f;
#pragma unroll
        for (int i = 0; i < KK; ++i) {
            float vf[8];
            unpack8(vd[i], vf);
#pragma unroll
            for (int j = 0; j < KK; ++j)
                acc = fmaf(vf[j], sc[i * KK + j], acc);
        }
        ob[ci] = f2bf(acc);
    }

    u32 od[4];
#pragma unroll
    for (int i = 0; i < 4; ++i)
        od[i] = (u32)ob[2 * i] | ((u32)ob[2 * i + 1] << 16);
    __builtin_memcpy(&O_l[px][c0], od, 16);
    __syncthreads();

    // ---- fused Wt conv + residual ----
#pragma unroll
    for (int c8 = 0; c8 < 8; ++c8) {
        uint4 d = *(const uint4*)&O_l[px][c8 * 8];
        float oc[8];
        unpack8(d, oc);
#pragma unroll
        for (int cc = 0; cc < 8; ++cc) {
            const int c = c8 * 8 + cc;
#pragma unroll
            for (int i = 0; i < 8; ++i)
                fin[i] = fmaf(Wt_l[c0 + i][c], oc[cc], fin[i]);
        }
    }

#pragma unroll
    for (int i = 0; i < 8; ++i)
        out[((size_t)(b * CC) + c0 + i) * HWSZ + hw] = fin[i];
}

// ---------------------------------------------------------------------------
extern "C" void kernel_launch(void* const* d_in, const int* in_sizes, int n_in,
                              void* d_out, int out_size, void* d_ws, size_t ws_size,
                              hipStream_t stream)
{
    const float* x  = (const float*)d_in[0];
    const float* Wk = (const float*)d_in[1];
    const float* Wq = (const float*)d_in[2];
    const float* Wv = (const float*)d_in[3];
    const float* Wt = (const float*)d_in[4];
    float* out = (float*)d_out;

    const size_t KP_ELEMS = (size_t)BB * CC * HH * ROWE;  // 4,587,520 bf16
    __hip_bfloat16* Kp = (__hip_bfloat16*)d_ws;
    __hip_bfloat16* Vp = Kp + KP_ELEMS;
    __hip_bfloat16* Qt = Vp + KP_ELEMS;                   // total ws 22.6 MB

    hipLaunchKernelGGL(kqv_kernel, dim3(768), dim3(256), 0, stream,
                       x, Wk, Wq, Wv, Kp, Qt, Vp);
    hipLaunchKernelGGL(attn_kernel, dim3(1024), dim3(256), 0, stream,
                       Kp, Qt, Vp, Wt, x, out);
}